// Round 9
// baseline (19.490 us; speedup 1.0000x reference)
//
#include <hip/hip_runtime.h>
#include <math.h>

#define DIM    128
#define DIM2   256
#define NSIGN  4
#define CCONST 0.618f
#define MB     8
#define NTHR   512

typedef short bf16x8 __attribute__((ext_vector_type(8)));
typedef float f32x4  __attribute__((ext_vector_type(4)));

#define MFMA(a,b,c) __builtin_amdgcn_mfma_f32_16x16x32_bf16((a),(b),(c),0,0,0)

union BU { uint4 q; bf16x8 b; };

__device__ __forceinline__ unsigned short f2bf(float f) {
    unsigned u = __float_as_uint(f);
    u += 0x7fffu + ((u >> 16) & 1u);          // round-to-nearest-even
    return (unsigned short)(u >> 16);
}
__device__ __forceinline__ float bf2f(unsigned short h) {
    return __uint_as_float(((unsigned)h) << 16);
}
__device__ __forceinline__ bf16x8 frag16(const unsigned short* p) {
    BU u; u.q = *(const uint4*)p; return u.b;
}

// ---------------- prep: pack 4 weight panels into MFMA fragment order ----------------
// pack m: [nt][kt][lane][e] with value B[kt*32 + 8*(lane>>4) + e][nt*16 + (lane&15)]
//   m=0: B = W1T (128x256)  B[r][c] = W1[c*128 + r]   (hi + lo planes)
//   m=1: B = W2T (256x128)  B[r][c] = W2[c*256 + r]   (hi only)
//   m=2: B = W2  (128x256)  B[r][c] = W2[r*256 + c]   (hi only)
//   m=3: B = W1  (256x128)  B[r][c] = W1[r*128 + c]   (hi only)
// pack stride 65536 ushort (hi plane 32768 ushort, lo plane 32768 ushort)
__global__ void prep_pack(const float* __restrict__ W1, const float* __restrict__ W2,
                          unsigned short* __restrict__ pk) {
    int tid  = blockIdx.x * 256 + threadIdx.x;   // 16384 threads
    int m    = tid >> 12;
    int f    = tid & 4095;
    int lane = f & 63;
    int tkt  = f >> 6;                           // nt*KT + kt
    int r0   = ((tkt & ((m == 0 || m == 2) ? 3 : 7)) * 32) + ((lane >> 4) << 3);
    int nt   = tkt / ((m == 0 || m == 2) ? 4 : 8);
    int c    = nt * 16 + (lane & 15);

    union { uint4 q; unsigned short u[8]; } H, L;
    #pragma unroll
    for (int e = 0; e < 8; ++e) {
        int r = r0 + e;
        float v;
        if      (m == 0) v = W1[c * DIM  + r];
        else if (m == 1) v = W2[c * DIM2 + r];
        else if (m == 2) v = W2[r * DIM2 + c];
        else             v = W1[r * DIM  + c];
        unsigned short hb = f2bf(v);
        H.u[e] = hb;
        L.u[e] = f2bf(v - bf2f(hb));
    }
    size_t base = (size_t)m * 65536 + (size_t)(tkt * 64 + lane) * 8;
    *(uint4*)(pk + base) = H.q;
    if (m == 0) *(uint4*)(pk + base + 32768) = L.q;
}

// ------------- fused main: MB=8, 8 waves/block, 2 blocks/CU (decoupled barriers) -------------
__global__ __launch_bounds__(NTHR, 4)
void fused_connection(const float* __restrict__ input_,
                      const float* __restrict__ b1,
                      const float* __restrict__ b2,
                      const unsigned short* __restrict__ pk,
                      float* __restrict__ out) {
    __shared__ __align__(16) float          vv [MB][132];   // v fp32
    __shared__ __align__(16) unsigned short xbH[MB][136];   // x hi plane
    __shared__ __align__(16) unsigned short xbL[MB][136];   // x lo plane
    __shared__ __align__(16) unsigned short vbH[MB][136];   // v hi plane
    __shared__ __align__(16) unsigned short aH [MB][264];   // a  bf16-hi
    __shared__ __align__(16) unsigned short mwH[MB][264];   // mw hi ; reused as mu hi
    __shared__ __align__(16) unsigned short vcH[MB][136];   // vc hi

    const int t    = threadIdx.x;
    const int lane = t & 63;
    const int w    = t >> 6;             // wave id 0..7
    const int b0   = blockIdx.x * MB;
    const int arow = lane & 7;           // A-frag batch row (rows 8-15 duplicate 0-7)
    const int ncol = lane & 15;          // B/C column component
    const int kg   = (lane >> 4) << 3;   // k-offset of this lane group
    const int rbase = (lane >> 4) << 2;  // C/D row base (verified m89 layout)
    const bool storer = (lane < 32);     // lanes owning C rows 0..7

    // ---- entry: prefetch pass-1 B hi frags (2 nt tiles) + biases ----
    uint4 b1hq[2][4];
    #pragma unroll
    for (int nt2 = 0; nt2 < 2; ++nt2)
        #pragma unroll
        for (int kt = 0; kt < 4; ++kt)
            b1hq[nt2][kt] = *(const uint4*)(pk + (size_t)((((w * 2 + nt2) * 4 + kt) * 64 + lane) * 8));
    const float b1v0 = b1[(w * 2 + 0) * 16 + ncol];
    const float b1v1 = b1[(w * 2 + 1) * 16 + ncol];
    const float b2v  = b2[w * 16 + ncol];

    // ---- phase 0: load x|v (1 float4/thread), convert, stage planes; v -> out ----
    {
        int prow = t >> 6;               // 0..7
        int pc   = (t & 63) * 4;         // 0..252
        const float4 f = *(const float4*)(input_ + (size_t)(b0 + prow) * DIM2 + pc);
        float fa[4] = {f.x, f.y, f.z, f.w};
        if (pc < DIM) {
            union { unsigned short u[4]; ushort4 q; } H, L;
            #pragma unroll
            for (int e = 0; e < 4; ++e) {
                unsigned short hb = f2bf(fa[e]);
                H.u[e] = hb;
                L.u[e] = f2bf(fa[e] - bf2f(hb));
            }
            *(ushort4*)&xbH[prow][pc] = H.q;
            *(ushort4*)&xbL[prow][pc] = L.q;
        } else {
            int c = pc - DIM;
            *(float4*)&vv[prow][c] = f;
            union { unsigned short u[4]; ushort4 q; } H;
            #pragma unroll
            for (int e = 0; e < 4; ++e) H.u[e] = f2bf(fa[e]);
            *(ushort4*)&vbH[prow][c] = H.q;
            *(float4*)(out + (size_t)(b0 + prow) * DIM2 + c) = f;   // v -> out[:, :128]
        }
    }
    __syncthreads();

    // ---- Pass 1 (nt = w*2+nt2): h = x.W1^T + b1 (3-term split), w = v.W1^T (hi) ----
    uint4 b2q[8];
    {
        // prefetch pass-2 B (hi)
        const unsigned short* p1 = pk + 65536;
        #pragma unroll
        for (int kt = 0; kt < 8; ++kt)
            b2q[kt] = *(const uint4*)(p1 + (size_t)((w * 8 + kt) * 64 + lane) * 8);

        #pragma unroll
        for (int nt2 = 0; nt2 < 2; ++nt2) {
            f32x4 ha = {0.f, 0.f, 0.f, 0.f};
            f32x4 wa = {0.f, 0.f, 0.f, 0.f};
            #pragma unroll
            for (int kt = 0; kt < 4; ++kt) {
                int k0 = kt * 32 + kg;
                bf16x8 xH = frag16(&xbH[arow][k0]);
                bf16x8 xL = frag16(&xbL[arow][k0]);
                bf16x8 vH = frag16(&vbH[arow][k0]);
                // lo plane sits +32768 USHORTS after the hi fragment
                const unsigned short* blp =
                    pk + (size_t)((((w * 2 + nt2) * 4 + kt) * 64 + lane) * 8) + 32768;
                BU bh; bh.q = b1hq[nt2][kt];
                BU bl; bl.q = *(const uint4*)blp;
                ha = MFMA(xH, bh.b, ha);
                ha = MFMA(xH, bl.b, ha);
                ha = MFMA(xL, bh.b, ha);
                wa = MFMA(vH, bh.b, wa);
            }
            if (storer) {
                int col  = (w * 2 + nt2) * 16 + ncol;
                float bias = nt2 ? b1v1 : b1v0;
                #pragma unroll
                for (int reg = 0; reg < 4; ++reg) {
                    int row = rbase + reg;
                    float hv = ha[reg] + bias;
                    bool  mk = hv > 0.f;
                    aH[row][col]  = f2bf(mk ? hv : 0.f);
                    mwH[row][col] = f2bf(mk ? wa[reg] : 0.f);
                }
            }
        }
    }
    __syncthreads();

    // ---- Pass 2 (ci-tile = w): z = a.W2^T + b2 -> s; t2 = mw.W2^T ; write vc ----
    float sreg[4];
    f32x4 t2a = {0.f, 0.f, 0.f, 0.f};
    uint4 b3q[2][4];
    {
        // prefetch pass-3 B (hi)
        const unsigned short* p2 = pk + 2 * 65536;
        #pragma unroll
        for (int nt2 = 0; nt2 < 2; ++nt2)
            #pragma unroll
            for (int kt = 0; kt < 4; ++kt)
                b3q[nt2][kt] = *(const uint4*)(p2 + (size_t)((((w * 2 + nt2) * 4 + kt) * 64 + lane) * 8));

        f32x4 za = {0.f, 0.f, 0.f, 0.f};
        #pragma unroll
        for (int kt = 0; kt < 8; ++kt) {
            int k0 = kt * 32 + kg;
            bf16x8 af = frag16(&aH[arow][k0]);
            bf16x8 mf = frag16(&mwH[arow][k0]);
            BU bh; bh.q = b2q[kt];
            za  = MFMA(af, bh.b, za);
            t2a = MFMA(mf, bh.b, t2a);
        }
        if (storer) {
            int   ci   = w * 16 + ncol;        // i in [0,128)
            float sg_i = (ci < NSIGN) ? -1.f : 1.f;
            #pragma unroll
            for (int reg = 0; reg < 4; ++reg) {
                int row = rbase + reg;
                float z = za[reg] + b2v;
                float s = 1.f / (1.f + __expf(-z));
                sreg[reg] = s;
                float vvl = vv[row][ci];
                vcH[row][ci] = f2bf(vvl * vvl * sg_i * s * (1.f - s));
            }
        }
    }
    __syncthreads();

    // ---- Pass 3 (nt = w*2+nt2): u = vc.W2 ; mu = mask*u -> mwH ----
    uint4 b4q[8];
    {
        // prefetch pass-4 B (hi)
        const unsigned short* p3 = pk + 3 * 65536;
        #pragma unroll
        for (int kt = 0; kt < 8; ++kt)
            b4q[kt] = *(const uint4*)(p3 + (size_t)((w * 8 + kt) * 64 + lane) * 8);

        bf16x8 cH[4];
        #pragma unroll
        for (int kt = 0; kt < 4; ++kt)
            cH[kt] = frag16(&vcH[arow][kt * 32 + kg]);
        #pragma unroll
        for (int nt2 = 0; nt2 < 2; ++nt2) {
            f32x4 ua = {0.f, 0.f, 0.f, 0.f};
            #pragma unroll
            for (int kt = 0; kt < 4; ++kt) {
                BU bh; bh.q = b3q[nt2][kt];
                ua = MFMA(cH[kt], bh.b, ua);
            }
            if (storer) {
                int ck = (w * 2 + nt2) * 16 + ncol;   // k in [0,256)
                #pragma unroll
                for (int reg = 0; reg < 4; ++reg) {
                    int row = rbase + reg;
                    bool mk = aH[row][ck] != 0;       // a>0 <=> stored bf16 nonzero
                    mwH[row][ck] = f2bf(mk ? ua[reg] : 0.f);
                }
            }
        }
    }
    __syncthreads();

    // ---- Pass 4 (cj-tile = w): t1 = mu.W1 ; epilogue dv ----
    {
        f32x4 t1a = {0.f, 0.f, 0.f, 0.f};
        #pragma unroll
        for (int kt = 0; kt < 8; ++kt) {
            bf16x8 mf = frag16(&mwH[arow][kt * 32 + kg]);
            BU bh; bh.q = b4q[kt];
            t1a = MFMA(mf, bh.b, t1a);
        }
        if (storer) {
            int   cj   = w * 16 + ncol;        // same col as pass 2 -> sreg/t2a align
            float sg_j = (cj < NSIGN) ? -1.f : 1.f;
            #pragma unroll
            for (int reg = 0; reg < 4; ++reg) {
                int row = rbase + reg;
                float s  = sreg[reg];
                float cv = sg_j * s * (1.f - s);
                float gi = 1.f / (sg_j * (s + CCONST));
                float vvl = vv[row][cj];
                float dv = fmaf(-gi, t1a[reg], 2.f * vvl * gi * cv * t2a[reg]);
                out[(size_t)(b0 + row) * DIM2 + DIM + cj] = dv;
            }
        }
    }
}

extern "C" void kernel_launch(void* const* d_in, const int* in_sizes, int n_in,
                              void* d_out, int out_size, void* d_ws, size_t ws_size,
                              hipStream_t stream) {
    // inputs: t, input_, W1, b1, W2, b2
    const float* input_ = (const float*)d_in[1];
    const float* W1 = (const float*)d_in[2];
    const float* b1 = (const float*)d_in[3];
    const float* W2 = (const float*)d_in[4];
    const float* b2 = (const float*)d_in[5];
    float* out = (float*)d_out;
    unsigned short* pk = (unsigned short*)d_ws;   // 4 packs x 128 KB = 512 KB

    const int batch = in_sizes[1] / DIM2;

    prep_pack<<<64, 256, 0, stream>>>(W1, W2, pk);
    fused_connection<<<batch / MB, NTHR, 0, stream>>>(input_, b1, b2, pk, out);
}

// Round 10
// 16.475 us; speedup vs baseline: 1.1830x; 1.1830x over previous
//
#include <hip/hip_runtime.h>
#include <math.h>

#define DIM    128
#define DIM2   256
#define NSIGN  4
#define CCONST 0.618f
#define MB     16
#define NTHR   512

typedef short bf16x8 __attribute__((ext_vector_type(8)));
typedef float f32x4  __attribute__((ext_vector_type(4)));

#define MFMA(a,b,c) __builtin_amdgcn_mfma_f32_16x16x32_bf16((a),(b),(c),0,0,0)

union BU { uint4 q; bf16x8 b; };

__device__ __forceinline__ unsigned short f2bf(float f) {
    unsigned u = __float_as_uint(f);
    u += 0x7fffu + ((u >> 16) & 1u);          // round-to-nearest-even
    return (unsigned short)(u >> 16);
}
__device__ __forceinline__ float bf2f(unsigned short h) {
    return __uint_as_float(((unsigned)h) << 16);
}
__device__ __forceinline__ bf16x8 frag16(const unsigned short* p) {
    BU u; u.q = *(const uint4*)p; return u.b;
}

// ---------------- prep: pack 4 weight panels into MFMA fragment order ----------------
// pack m: [nt][kt][lane][e] with value B[kt*32 + 8*(lane>>4) + e][nt*16 + (lane&15)]
//   m=0: B = W1T (128x256)  B[r][c] = W1[c*128 + r]   (hi + lo planes)
//   m=1: B = W2T (256x128)  B[r][c] = W2[c*256 + r]   (hi only)
//   m=2: B = W2  (128x256)  B[r][c] = W2[r*256 + c]   (hi only)
//   m=3: B = W1  (256x128)  B[r][c] = W1[r*128 + c]   (hi only)
// pack stride 65536 ushort (hi plane 32768 ushort, lo plane 32768 ushort)
// 8x wider than before: 65536 threads, 2 elements (one 4B store) per thread.
__global__ void prep_pack(const float* __restrict__ W1, const float* __restrict__ W2,
                          unsigned short* __restrict__ pk) {
    int tid  = blockIdx.x * 256 + threadIdx.x;   // 65536 threads
    int lane = tid & 63;
    int rest = tid >> 6;                          // 0..1023
    int es   = rest & 3;                          // e-pair index: e = es*2, es*2+1
    int tkt  = (rest >> 2) & 63;                  // nt*KT + kt
    int m    = rest >> 8;                         // 0..3
    int r0   = ((tkt & ((m == 0 || m == 2) ? 3 : 7)) * 32) + ((lane >> 4) << 3) + es * 2;
    int nt   = tkt / ((m == 0 || m == 2) ? 4 : 8);
    int c    = nt * 16 + (lane & 15);

    unsigned short h[2], l[2];
    #pragma unroll
    for (int d = 0; d < 2; ++d) {
        int r = r0 + d;
        float v;
        if      (m == 0) v = W1[c * DIM  + r];
        else if (m == 1) v = W2[c * DIM2 + r];
        else if (m == 2) v = W2[r * DIM2 + c];
        else             v = W1[r * DIM  + c];
        unsigned short hb = f2bf(v);
        h[d] = hb;
        if (m == 0) l[d] = f2bf(v - bf2f(hb));
    }
    size_t base = (size_t)m * 65536 + (size_t)(tkt * 64 + lane) * 8 + es * 2;
    *(unsigned*)(pk + base) = (unsigned)h[0] | ((unsigned)h[1] << 16);
    if (m == 0)
        *(unsigned*)(pk + base + 32768) = (unsigned)l[0] | ((unsigned)l[1] << 16);
}

// ---------------- fused main kernel (R6 structure: MB=16, 8 waves, staged prefetch) ----------------
__global__ __launch_bounds__(NTHR, 1)
void fused_connection(const float* __restrict__ input_,
                      const float* __restrict__ b1,
                      const float* __restrict__ b2,
                      const unsigned short* __restrict__ pk,
                      float* __restrict__ out) {
    __shared__ __align__(16) float          vv [MB][132];   // v fp32
    __shared__ __align__(16) unsigned short xbH[MB][136];   // x hi plane
    __shared__ __align__(16) unsigned short xbL[MB][136];   // x lo plane
    __shared__ __align__(16) unsigned short vbH[MB][136];   // v hi plane
    __shared__ __align__(16) unsigned short aH [MB][264];   // a  bf16-hi
    __shared__ __align__(16) unsigned short mwH[MB][264];   // mw hi ; reused as mu hi
    __shared__ __align__(16) unsigned short vcH[MB][136];   // vc hi

    const int t    = threadIdx.x;
    const int lane = t & 63;
    const int w    = t >> 6;             // wave id 0..7
    const int b0   = blockIdx.x * MB;
    const int arow = lane & 15;          // A-frag row / C-frag col component
    const int kg   = (lane >> 4) << 3;   // k-offset of this lane group
    const int rbase = (lane >> 4) << 2;  // C/D row base (verified m89 layout)

    // ---- issue the HBM input load FIRST (longest latency) ----
    const int prow = t >> 5;             // 0..15
    const int pc   = (t & 31) * 8;       // 0..248
    const float4* src = (const float4*)(input_ + (size_t)(b0 + prow) * DIM2 + pc);
    const float4 f0 = src[0];
    const float4 f1 = src[1];

    // ---- prefetch pass-1 B fragments (L2) + biases under the input-load shadow ----
    uint4 b1hq[2][4], b1lq[2][4];
    #pragma unroll
    for (int nt2 = 0; nt2 < 2; ++nt2)
        #pragma unroll
        for (int kt = 0; kt < 4; ++kt) {
            const unsigned short* bp = pk + (size_t)((((w * 2 + nt2) * 4 + kt) * 64 + lane) * 8);
            b1hq[nt2][kt] = *(const uint4*)bp;
            b1lq[nt2][kt] = *(const uint4*)(bp + 32768);
        }
    const float b1v0 = b1[(w * 2 + 0) * 16 + arow];
    const float b1v1 = b1[(w * 2 + 1) * 16 + arow];
    const float b2v  = b2[w * 16 + arow];

    // ---- phase 0: convert in-register, stage planes; v -> out ----
    {
        float fa[8] = {f0.x, f0.y, f0.z, f0.w, f1.x, f1.y, f1.z, f1.w};
        if (pc < DIM) {
            union { unsigned short u[8]; uint4 q; } H, L;
            #pragma unroll
            for (int e = 0; e < 8; ++e) {
                unsigned short hb = f2bf(fa[e]);
                H.u[e] = hb;
                L.u[e] = f2bf(fa[e] - bf2f(hb));
            }
            *(uint4*)&xbH[prow][pc] = H.q;
            *(uint4*)&xbL[prow][pc] = L.q;
        } else {
            int c = pc - DIM;
            *(float4*)&vv[prow][c]     = f0;
            *(float4*)&vv[prow][c + 4] = f1;
            union { unsigned short u[8]; uint4 q; } H;
            #pragma unroll
            for (int e = 0; e < 8; ++e) H.u[e] = f2bf(fa[e]);
            *(uint4*)&vbH[prow][c] = H.q;
            // v -> out[:, :128] straight from registers
            float4* op = (float4*)(out + (size_t)(b0 + prow) * DIM2 + c);
            op[0] = f0; op[1] = f1;
        }
    }
    __syncthreads();

    // ---- Pass 1: B=W1T -> h = x.W1^T + b1 (3-term split), w = v.W1^T (hi) ----
    uint4 b2q[8];
    {
        // prefetch pass-2 B
        const unsigned short* p1 = pk + 65536;
        #pragma unroll
        for (int kt = 0; kt < 8; ++kt)
            b2q[kt] = *(const uint4*)(p1 + (size_t)((w * 8 + kt) * 64 + lane) * 8);

        bf16x8 xH[4], xL[4], vH[4];
        #pragma unroll
        for (int kt = 0; kt < 4; ++kt) {
            int k0 = kt * 32 + kg;
            xH[kt] = frag16(&xbH[arow][k0]);
            xL[kt] = frag16(&xbL[arow][k0]);
            vH[kt] = frag16(&vbH[arow][k0]);
        }
        #pragma unroll
        for (int nt2 = 0; nt2 < 2; ++nt2) {
            int nt = w * 2 + nt2;
            f32x4 ha = {0.f, 0.f, 0.f, 0.f};
            f32x4 wa = {0.f, 0.f, 0.f, 0.f};
            #pragma unroll
            for (int kt = 0; kt < 4; ++kt) {
                BU bh, bl;
                bh.q = b1hq[nt2][kt];
                bl.q = b1lq[nt2][kt];
                ha = MFMA(xH[kt], bh.b, ha);
                ha = MFMA(xH[kt], bl.b, ha);
                ha = MFMA(xL[kt], bh.b, ha);
                wa = MFMA(vH[kt], bh.b, wa);
            }
            int col  = nt * 16 + arow;
            float bias = nt2 ? b1v1 : b1v0;
            #pragma unroll
            for (int reg = 0; reg < 4; ++reg) {
                int row = rbase + reg;
                float hv = ha[reg] + bias;
                bool  mk = hv > 0.f;
                aH[row][col]  = f2bf(mk ? hv : 0.f);
                mwH[row][col] = f2bf(mk ? wa[reg] : 0.f);
            }
        }
    }
    __syncthreads();

    // ---- Pass 2: B=W2T(hi) -> z = a.W2^T + b2 (-> s), t2 = mw.W2^T ; write vc ----
    float sreg[4];
    f32x4 t2a = {0.f, 0.f, 0.f, 0.f};
    uint4 b3q[2][4];
    {
        // prefetch pass-3 B
        const unsigned short* p2 = pk + 2 * 65536;
        #pragma unroll
        for (int nt2 = 0; nt2 < 2; ++nt2)
            #pragma unroll
            for (int kt = 0; kt < 4; ++kt)
                b3q[nt2][kt] = *(const uint4*)(p2 + (size_t)((((w * 2 + nt2) * 4 + kt) * 64 + lane) * 8));

        f32x4 za = {0.f, 0.f, 0.f, 0.f};
        #pragma unroll
        for (int kt = 0; kt < 8; ++kt) {
            int k0 = kt * 32 + kg;
            bf16x8 af = frag16(&aH[arow][k0]);
            bf16x8 mf = frag16(&mwH[arow][k0]);
            BU bh; bh.q = b2q[kt];
            za  = MFMA(af, bh.b, za);
            t2a = MFMA(mf, bh.b, t2a);
        }
        int   ci   = w * 16 + arow;            // i in [0,128)
        float sg_i = (ci < NSIGN) ? -1.f : 1.f;
        #pragma unroll
        for (int reg = 0; reg < 4; ++reg) {
            int row = rbase + reg;
            float z = za[reg] + b2v;
            float s = 1.f / (1.f + __expf(-z));
            sreg[reg] = s;
            float vvl = vv[row][ci];
            vcH[row][ci] = f2bf(vvl * vvl * sg_i * s * (1.f - s));
        }
    }
    __syncthreads();

    // ---- Pass 3: B=W2(hi) -> u = vc.W2 ; write mu = mask*u into mwH ----
    uint4 b4q[8];
    {
        // prefetch pass-4 B
        const unsigned short* p3 = pk + 3 * 65536;
        #pragma unroll
        for (int kt = 0; kt < 8; ++kt)
            b4q[kt] = *(const uint4*)(p3 + (size_t)((w * 8 + kt) * 64 + lane) * 8);

        bf16x8 cH[4];
        #pragma unroll
        for (int kt = 0; kt < 4; ++kt)
            cH[kt] = frag16(&vcH[arow][kt * 32 + kg]);
        #pragma unroll
        for (int nt2 = 0; nt2 < 2; ++nt2) {
            int nt = w * 2 + nt2;
            f32x4 ua = {0.f, 0.f, 0.f, 0.f};
            #pragma unroll
            for (int kt = 0; kt < 4; ++kt) {
                BU bh; bh.q = b3q[nt2][kt];
                ua = MFMA(cH[kt], bh.b, ua);
            }
            int ck = nt * 16 + arow;           // k in [0,256)
            #pragma unroll
            for (int reg = 0; reg < 4; ++reg) {
                int row = rbase + reg;
                bool mk = aH[row][ck] != 0;    // a>0 <=> stored bf16 nonzero
                mwH[row][ck] = f2bf(mk ? ua[reg] : 0.f);
            }
        }
    }
    __syncthreads();

    // ---- Pass 4: B=W1(hi) -> t1 = mu.W1 ; epilogue dv ----
    {
        f32x4 t1a = {0.f, 0.f, 0.f, 0.f};
        #pragma unroll
        for (int kt = 0; kt < 8; ++kt) {
            bf16x8 mf = frag16(&mwH[arow][kt * 32 + kg]);
            BU bh; bh.q = b4q[kt];
            t1a = MFMA(mf, bh.b, t1a);
        }
        int   cj   = w * 16 + arow;            // same col as pass 2 -> sreg/t2a align
        float sg_j = (cj < NSIGN) ? -1.f : 1.f;
        #pragma unroll
        for (int reg = 0; reg < 4; ++reg) {
            int row = rbase + reg;
            float s  = sreg[reg];
            float cv = sg_j * s * (1.f - s);
            float gi = 1.f / (sg_j * (s + CCONST));
            float vvl = vv[row][cj];
            float dv = fmaf(-gi, t1a[reg], 2.f * vvl * gi * cv * t2a[reg]);
            out[(size_t)(b0 + row) * DIM2 + DIM + cj] = dv;
        }
    }
}

extern "C" void kernel_launch(void* const* d_in, const int* in_sizes, int n_in,
                              void* d_out, int out_size, void* d_ws, size_t ws_size,
                              hipStream_t stream) {
    // inputs: t, input_, W1, b1, W2, b2
    const float* input_ = (const float*)d_in[1];
    const float* W1 = (const float*)d_in[2];
    const float* b1 = (const float*)d_in[3];
    const float* W2 = (const float*)d_in[4];
    const float* b2 = (const float*)d_in[5];
    float* out = (float*)d_out;
    unsigned short* pk = (unsigned short*)d_ws;   // 4 packs x 128 KB = 512 KB

    const int batch = in_sizes[1] / DIM2;

    prep_pack<<<256, 256, 0, stream>>>(W1, W2, pk);
    fused_connection<<<batch / MB, NTHR, 0, stream>>>(input_, b1, b2, pk, out);
}